// Round 7
// baseline (60.679 us; speedup 1.0000x reference)
//
#include <hip/hip_runtime.h>

typedef _Float16 f16x8 __attribute__((ext_vector_type(8)));
typedef float f32x4 __attribute__((ext_vector_type(4)));
typedef unsigned int u32x2 __attribute__((ext_vector_type(2)));

#define MROWS 65536

// ---- d_ws byte offsets ----
#define B1F_OFF 0u        // GEMM1 B frags: [2kt][16nt][64lane][8] f16 = 32768 B (K=64, no hi/lo dup)
#define B2F_OFF 65536u    // GEMM2 B frags: [8kt][16nt][64lane][8] f16 = 131072 B
#define TP_OFF 196608u    // phone_table @ W1[64:192]: [100][256] f32
#define TM_OFF 299008u    // midi_table @ W1[192:256]: [128][256] f32
#define BC_OFF 430080u    // fused bias: [256] f32
#define WFD_OFF 431104u   // fused f0/dur weights: [64][256] f32 (ends 496640)
#define HFRAG_OFF 524288u // stage1->stage2 packed A2 frags: 1024 blk x 32KB = 32 MiB
#define WS_NEED (524288u + 33554432u)

// Fragment k-slot mapping (all A and B fragments):
//   k = kt*32 + 4*(lane>>4) + (e&3) + 16*(e>>2)
// B fragments use a PERMUTED column layout: tile nt, lane c holds logical
// column (nt>>2)*64 + c*4 + (nt&3). In-wave (nt = wc*4 + j) each lane's four
// j-values are 4 CONSECUTIVE logical columns wc*64 + c*4 + {0..3}: table reads,
// LN params, bias and output stores are plain float4; the LN->GEMM2 repack is
// a pure per-lane 8B write (no shuffles).
// C/D: col_tile = lane&15 (permuted as above); row = (lane>>4)*4 + reg.
// Packed A2 granule index (16B) within a 64-row tile: g = (kt*4 + i)*64 + lane,
// lane = (row&15) + 16*(c&3), byte half = 8*((c>>2)&1)  [verified rounds 5-6].

// LDS A-frag swizzle used only by the fused fallback kernel.
__device__ __forceinline__ unsigned afoff(unsigned X) {
  return (X * 16u) ^ ((X & 0x38u) << 1);
}

__global__ __launch_bounds__(256) void prep_tables(
    const float* __restrict__ f0_w2, const float* __restrict__ f0_b2,
    const float* __restrict__ ptab, const float* __restrict__ mtab,
    const float* __restrict__ dur_w2, const float* __restrict__ dur_b2,
    const float* __restrict__ W1, const float* __restrict__ pb1,
    float* __restrict__ wsf) {
  const int r = blockIdx.x, n = threadIdx.x;
  if (r < 64) {  // Wfd row r
    float s = 0.f;
    if (r < 32) {
      for (int j = 0; j < 64; ++j) s = fmaf(f0_w2[r * 64 + j], W1[j * 256 + n], s);
    } else {
      for (int j = 0; j < 64; ++j) s = fmaf(dur_w2[(r - 32) * 64 + j], W1[(256 + j) * 256 + n], s);
    }
    wsf[WFD_OFF / 4 + r * 256 + n] = s;
  } else if (r < 164) {  // Tp row
    const int p = r - 64;
    float s = 0.f;
    for (int j = 0; j < 128; ++j) s = fmaf(ptab[p * 128 + j], W1[(64 + j) * 256 + n], s);
    wsf[TP_OFF / 4 + p * 256 + n] = s;
  } else if (r < 292) {  // Tm row
    const int m = r - 164;
    float s = 0.f;
    for (int j = 0; j < 64; ++j) s = fmaf(mtab[m * 64 + j], W1[(192 + j) * 256 + n], s);
    wsf[TM_OFF / 4 + m * 256 + n] = s;
  } else {  // fused bias
    float s = pb1[n];
    for (int j = 0; j < 64; ++j) {
      s = fmaf(f0_b2[j], W1[j * 256 + n], s);
      s = fmaf(dur_b2[j], W1[(256 + j) * 256 + n], s);
    }
    wsf[BC_OFF / 4 + n] = s;
  }
}

__global__ __launch_bounds__(64) void prep_frags(const float* __restrict__ W2, char* __restrict__ ws) {
  const float* Wfd = (const float*)(ws + WFD_OFF);
  const int t = blockIdx.x;
  const int l = threadIdx.x;
  const int qq = l >> 4, c = l & 15;
  if (t < 32) {  // B1: K=64 (no hi/lo duplication)
    const int kt = t >> 4, nt = t & 15;
    const int col = (nt >> 2) * 64 + c * 4 + (nt & 3);  // permuted column layout
    f16x8 v;
#pragma unroll
    for (int e = 0; e < 8; ++e) {
      const int k = kt * 32 + 4 * qq + (e & 3) + 16 * (e >> 2);
      v[e] = (_Float16)Wfd[k * 256 + col];
    }
    *(f16x8*)(ws + B1F_OFF + (unsigned)((kt * 16 + nt) * 64 + l) * 16u) = v;
  } else {  // B2 = proj_w2
    const int t2 = t - 32;
    const int kt = t2 >> 4, nt = t2 & 15;
    const int col = (nt >> 2) * 64 + c * 4 + (nt & 3);  // permuted column layout
    f16x8 v;
#pragma unroll
    for (int e = 0; e < 8; ++e) {
      const int k = kt * 32 + 4 * qq + (e & 3) + 16 * (e >> 2);
      v[e] = (_Float16)W2[k * 256 + col];
    }
    *(f16x8*)(ws + B2F_OFF + (unsigned)((kt * 16 + nt) * 64 + l) * 16u) = v;
  }
}

// ===================== split path: stage 1 =====================
// 64 rows/block, 4 col-group waves. Computes h = GEMM1 + tables, LN, ReLU,
// writes packed GEMM2 A-fragments (f16) to global scratch. LDS = 3KB, 1 barrier.
__global__ __launch_bounds__(256, 2) void enc_stage1(
    const float* __restrict__ f0g, const int* __restrict__ phone,
    const float* __restrict__ durg, const int* __restrict__ midi,
    const float* __restrict__ f0_w1, const float* __restrict__ f0_b1,
    const float* __restrict__ dur_w1, const float* __restrict__ dur_b1,
    const float* __restrict__ ln_g, const float* __restrict__ ln_b,
    const char* __restrict__ ws, char* __restrict__ hfrag) {
  __shared__ __align__(16) float partials[64 * 12];

  const int tid = threadIdx.x;
  const int l = tid & 63;
  const int wc = tid >> 6;
  const int q = l >> 4;
  const int c = l & 15;
  const int b = blockIdx.x;

  const float* Tp = (const float*)(ws + TP_OFF);
  const float* Tm = (const float*)(ws + TM_OFF);

  const float xf_all = f0g[b * 64 + l];
  const float xd_all = durg[b * 64 + l];
  const int ph_all = phone[b * 64 + l];
  const int md_all = midi[b * 64 + l];

  // A1 fragments in registers (K=64: kt0 = f0 MLP, kt1 = dur MLP), plain f16
  f16x8 a1[4][2];
#pragma unroll
  for (int i = 0; i < 4; ++i) {
    const float xf = __shfl(xf_all, i * 16 + c);
    const float xd = __shfl(xd_all, i * 16 + c);
#pragma unroll
    for (int kh = 0; kh < 2; ++kh) {
      f16x8 v;
#pragma unroll
      for (int e = 0; e < 8; ++e) {
        const int ki = 4 * q + (e & 3) + 16 * (e >> 2);  // 0..31
        const float wv = kh ? dur_w1[ki] : f0_w1[ki];
        const float bv = kh ? dur_b1[ki] : f0_b1[ki];
        const float x = kh ? xd : xf;
        v[e] = (_Float16)fmaxf(fmaf(x, wv, bv), 0.f);
      }
      a1[i][kh] = v;
    }
  }

  // GEMM1 (K=64)
  const f32x4 zero4 = {0.f, 0.f, 0.f, 0.f};
  f32x4 acc[4][4];
#pragma unroll
  for (int i = 0; i < 4; ++i)
#pragma unroll
    for (int j = 0; j < 4; ++j) acc[i][j] = zero4;
  {
    const f16x8* B1p = (const f16x8*)(ws + B1F_OFF);
#pragma unroll
    for (int kt = 0; kt < 2; ++kt) {
      f16x8 b4[4];
#pragma unroll
      for (int j = 0; j < 4; ++j) b4[j] = B1p[(kt * 16 + wc * 4 + j) * 64 + l];
#pragma unroll
      for (int i = 0; i < 4; ++i)
#pragma unroll
        for (int j = 0; j < 4; ++j)
          acc[i][j] = __builtin_amdgcn_mfma_f32_16x16x32_f16(a1[i][kt], b4[j], acc[i][j], 0, 0, 0);
    }
  }

  // += bias + Tp[phone] + Tm[midi]; LN partial sums
  const f32x4 bc4 = *(const f32x4*)((const float*)(ws + BC_OFF) + wc * 64 + c * 4);
  float psum[4][4], psq[4][4];
#pragma unroll
  for (int i = 0; i < 4; ++i) {
#pragma unroll
    for (int r = 0; r < 4; ++r) {
      const int ph = __shfl(ph_all, i * 16 + q * 4 + r);
      const int md = __shfl(md_all, i * 16 + q * 4 + r);
      const f32x4 tp4 = *(const f32x4*)(Tp + ph * 256 + wc * 64 + c * 4);
      const f32x4 tm4 = *(const f32x4*)(Tm + md * 256 + wc * 64 + c * 4);
      float s = 0.f, ss = 0.f;
#pragma unroll
      for (int j = 0; j < 4; ++j) {
        float v = acc[i][j][r] + bc4[j] + tp4[j] + tm4[j];
        acc[i][j][r] = v;
        s += v;
        ss = fmaf(v, v, ss);
      }
      psum[i][r] = s;
      psq[i][r] = ss;
    }
  }
#pragma unroll
  for (int i = 0; i < 4; ++i)
#pragma unroll
    for (int r = 0; r < 4; ++r) {
      float s = psum[i][r], ss = psq[i][r];
#pragma unroll
      for (int m = 1; m < 16; m <<= 1) {
        s += __shfl_xor(s, m, 64);
        ss += __shfl_xor(ss, m, 64);
      }
      psum[i][r] = s;
      psq[i][r] = ss;
    }
  if (c == 0) {
#pragma unroll
    for (int i = 0; i < 4; ++i)
#pragma unroll
      for (int r = 0; r < 4; ++r) {
        const int row = i * 16 + q * 4 + r;
        partials[row * 12 + wc * 2 + 0] = psum[i][r];
        partials[row * 12 + wc * 2 + 1] = psq[i][r];
      }
  }
  __syncthreads();

  // per-lane stats for row l (held in registers, distributed via bpermute)
  float mu_r, rs_r;
  {
    const f32x4 pa = *(const f32x4*)(partials + l * 12);
    const f32x4 pb = *(const f32x4*)(partials + l * 12 + 4);
    const float s = pa[0] + pa[2] + pb[0] + pb[2];
    const float ss = pa[1] + pa[3] + pb[1] + pb[3];
    mu_r = s * (1.f / 256.f);
    const float var = fmaxf(ss * (1.f / 256.f) - mu_r * mu_r, 0.f);
    rs_r = rsqrtf(var + 1e-5f);
  }

  // LN + ReLU + pack 8B straight to global frag buffer (layout = stage2 A-frags)
  const f32x4 g4 = *(const f32x4*)(ln_g + wc * 64 + c * 4);
  const f32x4 lb4 = *(const f32x4*)(ln_b + wc * 64 + c * 4);
  const int kt_pk = wc * 2 + (c >> 3);
  const int lp_base = 16 * (c & 3);
  const unsigned hoff = (unsigned)((c >> 2) & 1) * 8u;
  char* hb = hfrag + (size_t)b * 32768u;
#pragma unroll
  for (int i = 0; i < 4; ++i) {
#pragma unroll
    for (int r = 0; r < 4; ++r) {
      const int row = i * 16 + q * 4 + r;
      const float mu = __shfl(mu_r, row, 64);
      const float rstd = __shfl(rs_r, row, 64);
      unsigned short hw[4];
#pragma unroll
      for (int j = 0; j < 4; ++j) {
        float v = fmaf((acc[i][j][r] - mu) * rstd, g4[j], lb4[j]);
        v = fmaxf(v, 0.f);
        hw[j] = __builtin_bit_cast(unsigned short, (_Float16)v);
      }
      u32x2 pkt;
      pkt[0] = (unsigned)hw[0] | ((unsigned)hw[1] << 16);
      pkt[1] = (unsigned)hw[2] | ((unsigned)hw[3] << 16);
      const unsigned g = (unsigned)((kt_pk * 4 + i) * 64 + (q * 4 + r + lp_base));
      *(u32x2*)(hb + g * 16u + hoff) = pkt;
    }
  }
}

// ===================== split path: stage 2 =====================
// Pure frag-GEMM: no LDS, no barriers. 512 blocks x 8 waves; wave = 64 rows x
// 64 cols. A-frags read coalesced (1KB/wave/instr), B2 frags L2-hot.
__global__ __launch_bounds__(512, 2) void enc_stage2(
    const float* __restrict__ pb2, const char* __restrict__ ws,
    const char* __restrict__ hfrag, float* __restrict__ out) {
  const int tid = threadIdx.x;
  const int l = tid & 63;
  const int w = tid >> 6;
  const int wc = w & 3;   // column group
  const int wr = w >> 2;  // row half
  const int q = l >> 4;
  const int c = l & 15;
  const int b2 = blockIdx.x * 2 + wr;  // 64-row tile index 0..1023

  const f16x8* Ap = (const f16x8*)(hfrag + (size_t)b2 * 32768u);
  const f16x8* B2p = (const f16x8*)(ws + B2F_OFF);

  const f32x4 zero4 = {0.f, 0.f, 0.f, 0.f};
  f32x4 acc[4][4];
#pragma unroll
  for (int i = 0; i < 4; ++i)
#pragma unroll
    for (int j = 0; j < 4; ++j) acc[i][j] = zero4;

#pragma unroll
  for (int kt = 0; kt < 8; ++kt) {
    f16x8 a4[4], b4[4];
#pragma unroll
    for (int i = 0; i < 4; ++i) a4[i] = Ap[(kt * 4 + i) * 64 + l];
#pragma unroll
    for (int j = 0; j < 4; ++j) b4[j] = B2p[(kt * 16 + wc * 4 + j) * 64 + l];
#pragma unroll
    for (int i = 0; i < 4; ++i)
#pragma unroll
      for (int j = 0; j < 4; ++j)
        acc[i][j] = __builtin_amdgcn_mfma_f32_16x16x32_f16(a4[i], b4[j], acc[i][j], 0, 0, 0);
  }

  const f32x4 b24 = *(const f32x4*)(pb2 + wc * 64 + c * 4);
#pragma unroll
  for (int i = 0; i < 4; ++i)
#pragma unroll
    for (int r = 0; r < 4; ++r) {
      const int grow = b2 * 64 + i * 16 + q * 4 + r;
      f32x4 st;
#pragma unroll
      for (int j = 0; j < 4; ++j) st[j] = acc[i][j][r] + b24[j];
      __builtin_nontemporal_store(st, (f32x4*)(out + grow * 256 + wc * 64 + c * 4));
    }
}

// ===================== fused fallback (round-6 structure, K=64 GEMM1) =====================
__global__ __launch_bounds__(256, 2) void cond_enc_fused(
    const float* __restrict__ f0g, const int* __restrict__ phone,
    const float* __restrict__ durg, const int* __restrict__ midi,
    const float* __restrict__ f0_w1, const float* __restrict__ f0_b1,
    const float* __restrict__ dur_w1, const float* __restrict__ dur_b1,
    const float* __restrict__ ln_g, const float* __restrict__ ln_b,
    const float* __restrict__ pb2, const char* __restrict__ ws,
    float* __restrict__ out) {
  __shared__ __align__(16) unsigned char smem[32768 + 3072];
  unsigned char* Afrag = smem;
  float* partials = (float*)(smem + 32768);

  const int tid = threadIdx.x;
  const int l = tid & 63;
  const int wc = tid >> 6;
  const int q = l >> 4;
  const int c = l & 15;
  const int b = blockIdx.x;

  const float* Tp = (const float*)(ws + TP_OFF);
  const float* Tm = (const float*)(ws + TM_OFF);

  const float xf_all = f0g[b * 64 + l];
  const float xd_all = durg[b * 64 + l];
  const int ph_all = phone[b * 64 + l];
  const int md_all = midi[b * 64 + l];

  const f32x4 zero4 = {0.f, 0.f, 0.f, 0.f};
  f32x4 acc[4][4];
#pragma unroll
  for (int i = 0; i < 4; ++i)
#pragma unroll
    for (int j = 0; j < 4; ++j) acc[i][j] = zero4;
  {
    const f16x8* B1p = (const f16x8*)(ws + B1F_OFF);
#pragma unroll
    for (int i = 0; i < 4; ++i) {
      f16x8 a1[2];
      const float xf = __shfl(xf_all, i * 16 + c);
      const float xd = __shfl(xd_all, i * 16 + c);
#pragma unroll
      for (int kh = 0; kh < 2; ++kh) {
        f16x8 v;
#pragma unroll
        for (int e = 0; e < 8; ++e) {
          const int ki = 4 * q + (e & 3) + 16 * (e >> 2);
          const float wv = kh ? dur_w1[ki] : f0_w1[ki];
          const float bv = kh ? dur_b1[ki] : f0_b1[ki];
          const float x = kh ? xd : xf;
          v[e] = (_Float16)fmaxf(fmaf(x, wv, bv), 0.f);
        }
        a1[kh] = v;
      }
#pragma unroll
      for (int kt = 0; kt < 2; ++kt) {
        f16x8 b4[4];
#pragma unroll
        for (int j = 0; j < 4; ++j) b4[j] = B1p[(kt * 16 + wc * 4 + j) * 64 + l];
#pragma unroll
        for (int j = 0; j < 4; ++j)
          acc[i][j] = __builtin_amdgcn_mfma_f32_16x16x32_f16(a1[kt], b4[j], acc[i][j], 0, 0, 0);
      }
    }
  }

  const f32x4 bc4 = *(const f32x4*)((const float*)(ws + BC_OFF) + wc * 64 + c * 4);
  float psum[4][4], psq[4][4];
#pragma unroll
  for (int i = 0; i < 4; ++i) {
#pragma unroll
    for (int r = 0; r < 4; ++r) {
      const int ph = __shfl(ph_all, i * 16 + q * 4 + r);
      const int md = __shfl(md_all, i * 16 + q * 4 + r);
      const f32x4 tp4 = *(const f32x4*)(Tp + ph * 256 + wc * 64 + c * 4);
      const f32x4 tm4 = *(const f32x4*)(Tm + md * 256 + wc * 64 + c * 4);
      float s = 0.f, ss = 0.f;
#pragma unroll
      for (int j = 0; j < 4; ++j) {
        float v = acc[i][j][r] + bc4[j] + tp4[j] + tm4[j];
        acc[i][j][r] = v;
        s += v;
        ss = fmaf(v, v, ss);
      }
      psum[i][r] = s;
      psq[i][r] = ss;
    }
  }
#pragma unroll
  for (int i = 0; i < 4; ++i)
#pragma unroll
    for (int r = 0; r < 4; ++r) {
      float s = psum[i][r], ss = psq[i][r];
#pragma unroll
      for (int m = 1; m < 16; m <<= 1) {
        s += __shfl_xor(s, m, 64);
        ss += __shfl_xor(ss, m, 64);
      }
      psum[i][r] = s;
      psq[i][r] = ss;
    }
  if (c == 0) {
#pragma unroll
    for (int i = 0; i < 4; ++i)
#pragma unroll
      for (int r = 0; r < 4; ++r) {
        const int row = i * 16 + q * 4 + r;
        partials[row * 12 + wc * 2 + 0] = psum[i][r];
        partials[row * 12 + wc * 2 + 1] = psq[i][r];
      }
  }
  __syncthreads();

  const f32x4 g4 = *(const f32x4*)(ln_g + wc * 64 + c * 4);
  const f32x4 lb4 = *(const f32x4*)(ln_b + wc * 64 + c * 4);
  const int kt_pk = wc * 2 + (c >> 3);
  const int lp_base = 16 * (c & 3);
  const unsigned hoff = (unsigned)((c >> 2) & 1) * 8u;
#pragma unroll
  for (int i = 0; i < 4; ++i) {
#pragma unroll
    for (int r = 0; r < 4; ++r) {
      const int row = i * 16 + q * 4 + r;
      const f32x4 pa = *(const f32x4*)(partials + row * 12);
      const f32x4 pb = *(const f32x4*)(partials + row * 12 + 4);
      const float s = pa[0] + pa[2] + pb[0] + pb[2];
      const float ss = pa[1] + pa[3] + pb[1] + pb[3];
      const float mu = s * (1.f / 256.f);
      const float var = fmaxf(ss * (1.f / 256.f) - mu * mu, 0.f);
      const float rstd = rsqrtf(var + 1e-5f);
      unsigned short hw[4];
#pragma unroll
      for (int j = 0; j < 4; ++j) {
        float v = fmaf((acc[i][j][r] - mu) * rstd, g4[j], lb4[j]);
        v = fmaxf(v, 0.f);
        hw[j] = __builtin_bit_cast(unsigned short, (_Float16)v);
      }
      u32x2 pkt;
      pkt[0] = (unsigned)hw[0] | ((unsigned)hw[1] << 16);
      pkt[1] = (unsigned)hw[2] | ((unsigned)hw[3] << 16);
      const unsigned X = (unsigned)((kt_pk * 4 + i) * 64 + (q * 4 + r + lp_base));
      *(u32x2*)(Afrag + afoff(X) + hoff) = pkt;
    }
  }
  __syncthreads();

#pragma unroll
  for (int i = 0; i < 4; ++i)
#pragma unroll
    for (int j = 0; j < 4; ++j) acc[i][j] = zero4;
  {
    const f16x8* B2p = (const f16x8*)(ws + B2F_OFF);
#pragma unroll
    for (int kt = 0; kt < 8; ++kt) {
      f16x8 a4[4], b4[4];
#pragma unroll
      for (int i = 0; i < 4; ++i)
        a4[i] = *(const f16x8*)(Afrag + afoff((unsigned)((kt * 4 + i) * 64 + l)));
#pragma unroll
      for (int j = 0; j < 4; ++j) b4[j] = B2p[(kt * 16 + wc * 4 + j) * 64 + l];
#pragma unroll
      for (int i = 0; i < 4; ++i)
#pragma unroll
        for (int j = 0; j < 4; ++j)
          acc[i][j] = __builtin_amdgcn_mfma_f32_16x16x32_f16(a4[i], b4[j], acc[i][j], 0, 0, 0);
    }
  }
  const f32x4 b24 = *(const f32x4*)(pb2 + wc * 64 + c * 4);
#pragma unroll
  for (int i = 0; i < 4; ++i)
#pragma unroll
    for (int r = 0; r < 4; ++r) {
      const int grow = b * 64 + i * 16 + q * 4 + r;
      f32x4 st;
#pragma unroll
      for (int j = 0; j < 4; ++j) st[j] = acc[i][j][r] + b24[j];
      __builtin_nontemporal_store(st, (f32x4*)(out + grow * 256 + wc * 64 + c * 4));
    }
}

extern "C" void kernel_launch(void* const* d_in, const int* in_sizes, int n_in,
                              void* d_out, int out_size, void* d_ws, size_t ws_size,
                              hipStream_t stream) {
  (void)in_sizes; (void)n_in; (void)out_size;
  const float* f0 = (const float*)d_in[0];
  const int* phone = (const int*)d_in[1];
  const float* dur = (const float*)d_in[2];
  const int* midi = (const int*)d_in[3];
  const float* f0_w1 = (const float*)d_in[4];
  const float* f0_b1 = (const float*)d_in[5];
  const float* f0_w2 = (const float*)d_in[6];
  const float* f0_b2 = (const float*)d_in[7];
  const float* ptab = (const float*)d_in[8];
  const float* mtab = (const float*)d_in[9];
  const float* dur_w1 = (const float*)d_in[10];
  const float* dur_b1 = (const float*)d_in[11];
  const float* dur_w2 = (const float*)d_in[12];
  const float* dur_b2 = (const float*)d_in[13];
  const float* W1 = (const float*)d_in[14];
  const float* pb1 = (const float*)d_in[15];
  const float* ln_g = (const float*)d_in[16];
  const float* ln_b = (const float*)d_in[17];
  const float* W2 = (const float*)d_in[18];
  const float* pb2 = (const float*)d_in[19];
  char* ws = (char*)d_ws;
  float* out = (float*)d_out;

  prep_tables<<<293, 256, 0, stream>>>(f0_w2, f0_b2, ptab, mtab, dur_w2, dur_b2, W1, pb1, (float*)ws);
  prep_frags<<<160, 64, 0, stream>>>(W2, ws);
  if (ws_size >= (size_t)WS_NEED) {
    enc_stage1<<<1024, 256, 0, stream>>>(f0, phone, dur, midi, f0_w1, f0_b1, dur_w1, dur_b1,
                                         ln_g, ln_b, ws, ws + HFRAG_OFF);
    enc_stage2<<<512, 512, 0, stream>>>(pb2, ws, ws + HFRAG_OFF, out);
  } else {
    cond_enc_fused<<<1024, 256, 0, stream>>>(f0, phone, dur, midi, f0_w1, f0_b1, dur_w1, dur_b1,
                                             ln_g, ln_b, pb2, ws, out);
  }
}

// Round 8
// 39.239 us; speedup vs baseline: 1.5464x; 1.5464x over previous
//
#include <hip/hip_runtime.h>

typedef _Float16 f16x8 __attribute__((ext_vector_type(8)));
typedef float f32x4 __attribute__((ext_vector_type(4)));
typedef unsigned int u32x2 __attribute__((ext_vector_type(2)));

#define MROWS 65536
#define BM 128  // 4 waves x 32 rows
#define NBLK (MROWS / BM)  // 512

// ---- d_ws byte offsets ----
#define B1F_OFF 0u       // GEMM1 B frags: [2kt][16nt][64lane][8] f16 = 32768 B (K=64)
#define B2F_OFF 65536u   // GEMM2 B frags: [8kt][16nt][64lane][8] f16 = 131072 B
#define TP_OFF 196608u   // phone_table @ W1[64:192]: [100][256] f32
#define TM_OFF 299008u   // midi_table @ W1[192:256]: [128][256] f32
#define BC_OFF 430080u   // fused bias: [256] f32
#define WFD_OFF 431104u  // fused f0/dur weights: [64][256] f32 (ends 496640)

// Fragment k-slot mapping (all A and B fragments):
//   k = kt*32 + 4*(lane>>4) + (e&3) + 16*(e>>2)
// B fragments use a PERMUTED column layout: tile nt, lane c holds logical
// column (nt>>2)*64 + c*4 + (nt&3). A wave covering all 16 n-tiles has, per
// lane (q,c): cols {64g + 4c + b} for g=0..3,b=0..3 -> all table reads, LN
// params, bias and output stores are plain float4, and the LN->GEMM2 repack
// is a pure per-lane 8B write into WAVE-PRIVATE LDS (intra-wave dep only --
// the kernel has ZERO __syncthreads).
// C/D: col_tile = lane&15 (permuted as above); row = (lane>>4)*4 + reg.
// A2 granule within wave scratch: X = (kt*2+i)*64 + (row&15) + 16*(c&3),
// byte half = 8*((c>>2)&1); verified algebra: k_local 4*(c&7)+b == 4q'+(e&3)+16(e>>2).

// Wave-scratch swizzle: XOR addr bits [4:5] with X bits [4:5] -> pack writes
// spread over 16 banks (4-way on 8B ops, ~free), b128 reads stay conflict-free.
__device__ __forceinline__ unsigned a2off(unsigned X) {
  return (X * 16u) ^ (X & 0x30u);
}

__global__ __launch_bounds__(256) void prep_tables(
    const float* __restrict__ f0_w2, const float* __restrict__ f0_b2,
    const float* __restrict__ ptab, const float* __restrict__ mtab,
    const float* __restrict__ dur_w2, const float* __restrict__ dur_b2,
    const float* __restrict__ W1, const float* __restrict__ pb1,
    float* __restrict__ wsf) {
  const int r = blockIdx.x, n = threadIdx.x;
  if (r < 64) {  // Wfd row r
    float s = 0.f;
    if (r < 32) {
      for (int j = 0; j < 64; ++j) s = fmaf(f0_w2[r * 64 + j], W1[j * 256 + n], s);
    } else {
      for (int j = 0; j < 64; ++j) s = fmaf(dur_w2[(r - 32) * 64 + j], W1[(256 + j) * 256 + n], s);
    }
    wsf[WFD_OFF / 4 + r * 256 + n] = s;
  } else if (r < 164) {  // Tp row
    const int p = r - 64;
    float s = 0.f;
    for (int j = 0; j < 128; ++j) s = fmaf(ptab[p * 128 + j], W1[(64 + j) * 256 + n], s);
    wsf[TP_OFF / 4 + p * 256 + n] = s;
  } else if (r < 292) {  // Tm row
    const int m = r - 164;
    float s = 0.f;
    for (int j = 0; j < 64; ++j) s = fmaf(mtab[m * 64 + j], W1[(192 + j) * 256 + n], s);
    wsf[TM_OFF / 4 + m * 256 + n] = s;
  } else {  // fused bias
    float s = pb1[n];
    for (int j = 0; j < 64; ++j) {
      s = fmaf(f0_b2[j], W1[j * 256 + n], s);
      s = fmaf(dur_b2[j], W1[(256 + j) * 256 + n], s);
    }
    wsf[BC_OFF / 4 + n] = s;
  }
}

__global__ __launch_bounds__(64) void prep_frags(const float* __restrict__ W2, char* __restrict__ ws) {
  const float* Wfd = (const float*)(ws + WFD_OFF);
  const int t = blockIdx.x;
  const int l = threadIdx.x;
  const int qq = l >> 4, c = l & 15;
  if (t < 32) {  // B1: K=64
    const int kt = t >> 4, nt = t & 15;
    const int col = (nt >> 2) * 64 + c * 4 + (nt & 3);  // permuted column layout
    f16x8 v;
#pragma unroll
    for (int e = 0; e < 8; ++e) {
      const int k = kt * 32 + 4 * qq + (e & 3) + 16 * (e >> 2);
      v[e] = (_Float16)Wfd[k * 256 + col];
    }
    *(f16x8*)(ws + B1F_OFF + (unsigned)((kt * 16 + nt) * 64 + l) * 16u) = v;
  } else {  // B2 = proj_w2
    const int t2 = t - 32;
    const int kt = t2 >> 4, nt = t2 & 15;
    const int col = (nt >> 2) * 64 + c * 4 + (nt & 3);  // permuted column layout
    f16x8 v;
#pragma unroll
    for (int e = 0; e < 8; ++e) {
      const int k = kt * 32 + 4 * qq + (e & 3) + 16 * (e >> 2);
      v[e] = (_Float16)W2[k * 256 + col];
    }
    *(f16x8*)(ws + B2F_OFF + (unsigned)((kt * 16 + nt) * 64 + l) * 16u) = v;
  }
}

// Barrier-free main kernel: each wave owns 32 rows x 256 cols end-to-end.
__global__ __launch_bounds__(256, 2) void cond_enc_main(
    const float* __restrict__ f0g, const int* __restrict__ phone,
    const float* __restrict__ durg, const int* __restrict__ midi,
    const float* __restrict__ f0_w1, const float* __restrict__ f0_b1,
    const float* __restrict__ dur_w1, const float* __restrict__ dur_b1,
    const float* __restrict__ ln_g, const float* __restrict__ ln_b,
    const float* __restrict__ pb2, const char* __restrict__ ws,
    float* __restrict__ out) {
  // Wave-private A2-frag scratch: 16 frags x 1KB per wave. NO barriers anywhere.
  __shared__ __align__(16) unsigned char smem[4 * 16384];

  const int tid = threadIdx.x;
  const int l = tid & 63;
  const int w = tid >> 6;  // wave 0..3
  const int q = l >> 4;    // 0..3
  const int c = l & 15;    // 0..15
  const int rowbase = blockIdx.x * BM + w * 32;
  unsigned char* Asc = smem + w * 16384;

  const float* Tp = (const float*)(ws + TP_OFF);
  const float* Tm = (const float*)(ws + TM_OFF);

  // one coalesced load per lane (lane l&31 covers row rowbase + (l&31))
  const int rl = l & 31;
  const float xf_all = f0g[rowbase + rl];
  const float xd_all = durg[rowbase + rl];
  const int ph_all = phone[rowbase + rl];
  const int md_all = midi[rowbase + rl];

  // ---- A1 fragments in registers (K=64: kt0 = f0 MLP, kt1 = dur MLP) ----
  f16x8 a1[2][2];  // [i M-tile][kt]
#pragma unroll
  for (int i = 0; i < 2; ++i) {
    const float xf = __shfl(xf_all, i * 16 + c);
    const float xd = __shfl(xd_all, i * 16 + c);
#pragma unroll
    for (int kh = 0; kh < 2; ++kh) {
      f16x8 v;
#pragma unroll
      for (int e = 0; e < 8; ++e) {
        const int ki = 4 * q + (e & 3) + 16 * (e >> 2);  // 0..31
        const float wv = kh ? dur_w1[ki] : f0_w1[ki];
        const float bv = kh ? dur_b1[ki] : f0_b1[ki];
        const float x = kh ? xd : xf;
        v[e] = (_Float16)fmaxf(fmaf(x, wv, bv), 0.f);
      }
      a1[i][kh] = v;
    }
  }

  // ---- GEMM1 (K=64): acc[i][nt], nt spans ALL 16 col-tiles ----
  const f32x4 zero4 = {0.f, 0.f, 0.f, 0.f};
  f32x4 acc[2][16];
#pragma unroll
  for (int i = 0; i < 2; ++i)
#pragma unroll
    for (int nt = 0; nt < 16; ++nt) acc[i][nt] = zero4;
  {
    const f16x8* B1p = (const f16x8*)(ws + B1F_OFF);
#pragma unroll
    for (int kt = 0; kt < 2; ++kt) {
      f16x8 bfr[16];
#pragma unroll
      for (int nt = 0; nt < 16; ++nt) bfr[nt] = B1p[(kt * 16 + nt) * 64 + l];
#pragma unroll
      for (int i = 0; i < 2; ++i)
#pragma unroll
        for (int nt = 0; nt < 16; ++nt)
          acc[i][nt] = __builtin_amdgcn_mfma_f32_16x16x32_f16(a1[i][kt], bfr[nt], acc[i][nt], 0, 0, 0);
    }
  }

  // ---- epilogue + LN + pack, fully per-wave (no LDS partials, no barrier) ----
  const float* bcp = (const float*)(ws + BC_OFF);
  f32x4 bc4[4], g4[4], lb4[4];
#pragma unroll
  for (int g = 0; g < 4; ++g) {
    bc4[g] = *(const f32x4*)(bcp + g * 64 + c * 4);
    g4[g] = *(const f32x4*)(ln_g + g * 64 + c * 4);
    lb4[g] = *(const f32x4*)(ln_b + g * 64 + c * 4);
  }
  const int lp_base = 16 * (c & 3);
  const unsigned hoff = (unsigned)((c >> 2) & 1) * 8u;
#pragma unroll
  for (int i = 0; i < 2; ++i) {
#pragma unroll
    for (int r = 0; r < 4; ++r) {
      const int rrel = i * 16 + q * 4 + r;
      const int ph = __shfl(ph_all, rrel);
      const int md = __shfl(md_all, rrel);
      f32x4 tp4[4], tm4[4];
#pragma unroll
      for (int g = 0; g < 4; ++g) {
        tp4[g] = *(const f32x4*)(Tp + ph * 256 + g * 64 + c * 4);
        tm4[g] = *(const f32x4*)(Tm + md * 256 + g * 64 + c * 4);
      }
      float s = 0.f, ss = 0.f;
#pragma unroll
      for (int nt = 0; nt < 16; ++nt) {
        const int g = nt >> 2, bq = nt & 3;
        float v = acc[i][nt][r] + bc4[g][bq] + tp4[g][bq] + tm4[g][bq];
        acc[i][nt][r] = v;
        s += v;
        ss = fmaf(v, v, ss);
      }
      // full 256-col row sum lives inside this wave's 16 col-lanes
#pragma unroll
      for (int m = 1; m < 16; m <<= 1) {
        s += __shfl_xor(s, m, 64);
        ss += __shfl_xor(ss, m, 64);
      }
      const float mu = s * (1.f / 256.f);
      const float var = fmaxf(ss * (1.f / 256.f) - mu * mu, 0.f);
      const float rstd = rsqrtf(var + 1e-5f);
      // LN + ReLU + pack: per g, one 8B write into wave scratch
#pragma unroll
      for (int g = 0; g < 4; ++g) {
        unsigned short hw[4];
#pragma unroll
        for (int bq = 0; bq < 4; ++bq) {
          float v = fmaf((acc[i][4 * g + bq][r] - mu) * rstd, g4[g][bq], lb4[g][bq]);
          v = fmaxf(v, 0.f);
          hw[bq] = __builtin_bit_cast(unsigned short, (_Float16)v);
        }
        u32x2 pkt;
        pkt[0] = (unsigned)hw[0] | ((unsigned)hw[1] << 16);
        pkt[1] = (unsigned)hw[2] | ((unsigned)hw[3] << 16);
        const int kt = 2 * g + (c >> 3);
        const unsigned X = (unsigned)((kt * 2 + i) * 64 + (q * 4 + r + lp_base));
        *(u32x2*)(Asc + a2off(X) + hoff) = pkt;
      }
    }
  }
  // intra-wave LDS RAW: compiler emits lgkmcnt wait; no __syncthreads needed.

  // ---- GEMM2 (K=256): acc reused ----
#pragma unroll
  for (int i = 0; i < 2; ++i)
#pragma unroll
    for (int nt = 0; nt < 16; ++nt) acc[i][nt] = zero4;
  {
    const f16x8* B2p = (const f16x8*)(ws + B2F_OFF);
#pragma unroll
    for (int kt = 0; kt < 8; ++kt) {
      f16x8 a0 = *(const f16x8*)(Asc + a2off((unsigned)((kt * 2 + 0) * 64 + l)));
      f16x8 a1f = *(const f16x8*)(Asc + a2off((unsigned)((kt * 2 + 1) * 64 + l)));
      f16x8 bfr[16];
#pragma unroll
      for (int nt = 0; nt < 16; ++nt) bfr[nt] = B2p[(kt * 16 + nt) * 64 + l];
#pragma unroll
      for (int nt = 0; nt < 16; ++nt) {
        acc[0][nt] = __builtin_amdgcn_mfma_f32_16x16x32_f16(a0, bfr[nt], acc[0][nt], 0, 0, 0);
        acc[1][nt] = __builtin_amdgcn_mfma_f32_16x16x32_f16(a1f, bfr[nt], acc[1][nt], 0, 0, 0);
      }
    }
  }

  // ---- store: float4 nt-stores ----
  f32x4 b24[4];
#pragma unroll
  for (int g = 0; g < 4; ++g) b24[g] = *(const f32x4*)(pb2 + g * 64 + c * 4);
#pragma unroll
  for (int i = 0; i < 2; ++i)
#pragma unroll
    for (int r = 0; r < 4; ++r) {
      const int grow = rowbase + i * 16 + q * 4 + r;
#pragma unroll
      for (int g = 0; g < 4; ++g) {
        f32x4 st;
#pragma unroll
        for (int bq = 0; bq < 4; ++bq) st[bq] = acc[i][4 * g + bq][r] + b24[g][bq];
        __builtin_nontemporal_store(st, (f32x4*)(out + grow * 256 + g * 64 + c * 4));
      }
    }
}

extern "C" void kernel_launch(void* const* d_in, const int* in_sizes, int n_in,
                              void* d_out, int out_size, void* d_ws, size_t ws_size,
                              hipStream_t stream) {
  (void)in_sizes; (void)n_in; (void)out_size; (void)ws_size;
  const float* f0 = (const float*)d_in[0];
  const int* phone = (const int*)d_in[1];
  const float* dur = (const float*)d_in[2];
  const int* midi = (const int*)d_in[3];
  const float* f0_w1 = (const float*)d_in[4];
  const float* f0_b1 = (const float*)d_in[5];
  const float* f0_w2 = (const float*)d_in[6];
  const float* f0_b2 = (const float*)d_in[7];
  const float* ptab = (const float*)d_in[8];
  const float* mtab = (const float*)d_in[9];
  const float* dur_w1 = (const float*)d_in[10];
  const float* dur_b1 = (const float*)d_in[11];
  const float* dur_w2 = (const float*)d_in[12];
  const float* dur_b2 = (const float*)d_in[13];
  const float* W1 = (const float*)d_in[14];
  const float* pb1 = (const float*)d_in[15];
  const float* ln_g = (const float*)d_in[16];
  const float* ln_b = (const float*)d_in[17];
  const float* W2 = (const float*)d_in[18];
  const float* pb2 = (const float*)d_in[19];
  char* ws = (char*)d_ws;
  float* out = (float*)d_out;

  prep_tables<<<293, 256, 0, stream>>>(f0_w2, f0_b2, ptab, mtab, dur_w2, dur_b2, W1, pb1, (float*)ws);
  prep_frags<<<160, 64, 0, stream>>>(W2, ws);
  cond_enc_main<<<NBLK, 256, 0, stream>>>(f0, phone, dur, midi, f0_w1, f0_b1, dur_w1, dur_b1,
                                          ln_g, ln_b, pb2, ws, out);
}